// Round 3
// baseline (693.856 us; speedup 1.0000x reference)
//
#include <hip/hip_runtime.h>
#include <hip/hip_bf16.h>

// ExpertODEEnsemble: E=8, D=64, H=512, B=32768.
// R3: 128-row blocks (halve L2 weight traffic), depth-2 A / depth-1 B register
// prefetch (cover L2 latency), Pade tanh + v_cvt_pk_bf16_f32 epilogue, bias in
// acc init, layer4 = 8 tiles for 8 waves (no cross-wave reduction).

typedef unsigned short ushort_t;
typedef unsigned int u32;
typedef unsigned long long u64;
typedef __attribute__((ext_vector_type(8))) short short8;
typedef __attribute__((ext_vector_type(4))) float floatx4;
typedef __attribute__((ext_vector_type(16))) float floatx16;
typedef __attribute__((ext_vector_type(4))) int intx4;

// ws layout (bytes); granule = 16 B = 8 bf16 along k
#define W1A_OFF 0u          // per e: [kc0..3][o0..15][lane]   4096 granules
#define W2A_OFF 524288u     // per e: [kc0..31][o0..15][lane] 32768 granules
#define W3A_OFF 4718592u
#define W4A_OFF 8912896u    // per e: [kc0..31][o0..1][lane]   4096 granules
#define XB_OFF  9437184u    // x row-major bf16 [32768][64]
#define B1E_OFF 13631488u   // b1_eff fp32 [8][512]

static __device__ __forceinline__ u32 pk2bf(float a, float b) {
  union { __hip_bfloat162 h; u32 u; } v;
  v.h = __float22bfloat162_rn(make_float2(a, b));
  return v.u;
}

static __device__ __forceinline__ float pade_tanh(float x) {
  // tanh x = x(945+105x^2+x^4)/(945+420x^2+15x^4); |err|<=1e-4 for |x|<=2
  float x2 = x * x;
  float num = __builtin_fmaf(x2, __builtin_fmaf(x2, 1.0f, 105.0f), 945.0f);
  float den = __builtin_fmaf(x2, __builtin_fmaf(x2, 15.0f, 420.0f), 945.0f);
  return x * num * __builtin_amdgcn_rcpf(den);
}

static __device__ __forceinline__ void ald16(const void* g, void* l) {
  __builtin_amdgcn_global_load_lds((__attribute__((address_space(1))) void*)g,
                                   (__attribute__((address_space(3))) void*)l,
                                   16, 0, 0);
}

static __device__ __forceinline__ floatx16 mfma32(short8 a, short8 b, floatx16 c) {
  return __builtin_amdgcn_mfma_f32_32x32x16_bf16(a, b, c, 0, 0, 0);
}

// ---------------- prep: one 16B granule per thread, float4 reads -------------
__global__ __launch_bounds__(256) void prep_kernel(
    const float* __restrict__ t, const float* __restrict__ x,
    const float* __restrict__ omega, const float* __restrict__ W1,
    const float* __restrict__ b1, const float* __restrict__ W2,
    const float* __restrict__ W3, const float* __restrict__ W4,
    char* __restrict__ ws) {
  int i = blockIdx.x * 256 + threadIdx.x;
  if (i < 32768) {                       // W1A (stride 67 -> scalar reads)
    int e = i >> 12, r = i & 4095;
    int lane = r & 63, og = r >> 6, o = og & 15, kc = og >> 4;
    int outr = o * 32 + (lane & 31), k0 = kc * 16 + (lane >> 5) * 8;
    const float* s = W1 + (e * 512 + outr) * 67 + k0;
    ((intx4*)(ws + W1A_OFF))[i] = (intx4){
        (int)pk2bf(s[0], s[1]), (int)pk2bf(s[2], s[3]),
        (int)pk2bf(s[4], s[5]), (int)pk2bf(s[6], s[7])};
    return;
  }
  i -= 32768;
  if (i < 262144) {                      // W2A
    int e = i >> 15, r = i & 32767;
    int lane = r & 63, og = r >> 6, o = og & 15, kc = og >> 4;
    int outr = o * 32 + (lane & 31), k0 = kc * 16 + (lane >> 5) * 8;
    const floatx4* s = (const floatx4*)(W2 + (e * 512 + outr) * 512 + k0);
    floatx4 lo = s[0], hi = s[1];
    ((intx4*)(ws + W2A_OFF))[i] = (intx4){
        (int)pk2bf(lo[0], lo[1]), (int)pk2bf(lo[2], lo[3]),
        (int)pk2bf(hi[0], hi[1]), (int)pk2bf(hi[2], hi[3])};
    return;
  }
  i -= 262144;
  if (i < 262144) {                      // W3A
    int e = i >> 15, r = i & 32767;
    int lane = r & 63, og = r >> 6, o = og & 15, kc = og >> 4;
    int outr = o * 32 + (lane & 31), k0 = kc * 16 + (lane >> 5) * 8;
    const floatx4* s = (const floatx4*)(W3 + (e * 512 + outr) * 512 + k0);
    floatx4 lo = s[0], hi = s[1];
    ((intx4*)(ws + W3A_OFF))[i] = (intx4){
        (int)pk2bf(lo[0], lo[1]), (int)pk2bf(lo[2], lo[3]),
        (int)pk2bf(hi[0], hi[1]), (int)pk2bf(hi[2], hi[3])};
    return;
  }
  i -= 262144;
  if (i < 32768) {                       // W4A
    int e = i >> 12, r = i & 4095;
    int lane = r & 63, og = r >> 6, o = og & 1, kc = og >> 1;
    int outr = o * 32 + (lane & 31), k0 = kc * 16 + (lane >> 5) * 8;
    const floatx4* s = (const floatx4*)(W4 + (e * 64 + outr) * 512 + k0);
    floatx4 lo = s[0], hi = s[1];
    ((intx4*)(ws + W4A_OFF))[i] = (intx4){
        (int)pk2bf(lo[0], lo[1]), (int)pk2bf(lo[2], lo[3]),
        (int)pk2bf(hi[0], hi[1]), (int)pk2bf(hi[2], hi[3])};
    return;
  }
  i -= 32768;
  if (i < 262144) {                      // x -> bf16, row-major
    const floatx4* s = (const floatx4*)(x + i * 8);
    floatx4 lo = s[0], hi = s[1];
    ((intx4*)(ws + XB_OFF))[i] = (intx4){
        (int)pk2bf(lo[0], lo[1]), (int)pk2bf(lo[2], lo[3]),
        (int)pk2bf(hi[0], hi[1]), (int)pk2bf(hi[2], hi[3])};
    return;
  }
  i -= 262144;
  if (i < 4096) {                        // b1_eff: fold t/sin/cos cols of W1
    float tv = t[0];
    int e = i >> 9;
    float om = omega[e];
    ((float*)(ws + B1E_OFF))[i] = b1[i] + tv * W1[i * 67 + 64]
        + sinf(om * tv) * W1[i * 67 + 65] + cosf(om * tv) * W1[i * 67 + 66];
  }
}

// act LDS: granule f(row, koct) = (koct>>1)*260 + ((row>>5)&3)*64
//          + (koct&1)*32 + (row&31);  rows 0..127, koct 0..63.
// B-frag (kc,nt): granules kc*260 + nt*64 + lane  -> stride-1 1KB, conflict-free.

template <int NKC>
static __device__ __forceinline__ void mlp_layer(
    char* __restrict__ smem, int lane, int w, int q1, int r31,
    const short8* __restrict__ A, const float* __restrict__ bias) {
  const short8* Ap = A + (2 * w) * 64 + lane;   // granule (kc*16 + 2w+ol)*64+lane
  floatx16 acc[2][4];
#pragma unroll
  for (int ol = 0; ol < 2; ++ol) {
    int fe0 = (2 * w + ol) * 32 + 4 * q1;
#pragma unroll
    for (int g = 0; g < 4; ++g) {
      floatx4 bv = *(const floatx4*)(bias + fe0 + 8 * g);
#pragma unroll
      for (int nt = 0; nt < 4; ++nt) {
        acc[ol][nt][4 * g + 0] = bv[0];
        acc[ol][nt][4 * g + 1] = bv[1];
        acc[ol][nt][4 * g + 2] = bv[2];
        acc[ol][nt][4 * g + 3] = bv[3];
      }
    }
  }
  short8 a0[2], a1[2], b[4];
  a0[0] = Ap[0];    a0[1] = Ap[64];
  a1[0] = Ap[1024]; a1[1] = Ap[1024 + 64];       // depth-2 A prefetch
#pragma unroll
  for (int nt = 0; nt < 4; ++nt)
    b[nt] = *(const short8*)(smem + ((nt * 64 + lane) << 4));

#pragma unroll 4
  for (int kc = 0; kc < NKC; ++kc) {
    short8 ac0 = a0[0], ac1 = a0[1];
    a0[0] = a1[0]; a0[1] = a1[1];
    a1[0] = Ap[(kc + 2) * 1024];                 // unguarded: lands in ws, unused
    a1[1] = Ap[(kc + 2) * 1024 + 64];
    short8 bc0 = b[0], bc1 = b[1], bc2 = b[2], bc3 = b[3];
#pragma unroll
    for (int nt = 0; nt < 4; ++nt)
      b[nt] = *(const short8*)(smem + (((kc + 1) * 260 + nt * 64 + lane) << 4));
    acc[0][0] = mfma32(ac0, bc0, acc[0][0]);
    acc[0][1] = mfma32(ac0, bc1, acc[0][1]);
    acc[0][2] = mfma32(ac0, bc2, acc[0][2]);
    acc[0][3] = mfma32(ac0, bc3, acc[0][3]);
    acc[1][0] = mfma32(ac1, bc0, acc[1][0]);
    acc[1][1] = mfma32(ac1, bc1, acc[1][1]);
    acc[1][2] = mfma32(ac1, bc2, acc[1][2]);
    acc[1][3] = mfma32(ac1, bc3, acc[1][3]);
  }
  __syncthreads();                               // all B reads done
#pragma unroll
  for (int ol = 0; ol < 2; ++ol) {
    int o_abs = 2 * w + ol;
#pragma unroll
    for (int g = 0; g < 4; ++g) {
      int koct = o_abs * 4 + g;
      char* base = smem + ((((koct >> 1) * 260 + (koct & 1) * 32 + r31) << 4) + q1 * 8);
#pragma unroll
      for (int nt = 0; nt < 4; ++nt) {
        float v0 = pade_tanh(acc[ol][nt][4 * g + 0]);
        float v1 = pade_tanh(acc[ol][nt][4 * g + 1]);
        float v2 = pade_tanh(acc[ol][nt][4 * g + 2]);
        float v3 = pade_tanh(acc[ol][nt][4 * g + 3]);
        u32 lo = pk2bf(v0, v1), hi = pk2bf(v2, v3);
        *(u64*)(base + nt * 1024) = ((u64)hi << 32) | lo;
      }
    }
  }
  __syncthreads();                               // act_{n+1} visible
}

__global__ __launch_bounds__(512, 2) void fused_kernel(
    const char* __restrict__ ws, const float* __restrict__ b2,
    const float* __restrict__ b3, const float* __restrict__ b4,
    const float* __restrict__ ew, float* __restrict__ out) {
  __shared__ char smem[137280];          // 32*260*16 + one pad row (unguarded pf)
  const int t = threadIdx.x, lane = t & 63, w = t >> 6;
  const int q1 = lane >> 5, r31 = lane & 31;
  const int e = blockIdx.x & 7;          // expert -> XCD L2 affinity
  const int row0 = (blockIdx.x >> 3) << 7;       // 128-row tile

  // stage x (kc 0..3): 2 shots/wave, wave-uniform LDS base + lane*16
  const ushort_t* xb = (const ushort_t*)(ws + XB_OFF);
#pragma unroll
  for (int s = 0; s < 2; ++s) {
    int u = w + 8 * s, v = u >> 2, rg = u & 3;
    ald16(xb + (row0 + rg * 32 + r31) * 64 + (2 * v + q1) * 8,
          smem + ((v * 260 + rg * 64) << 4));
  }
  __syncthreads();

  mlp_layer<4>(smem, lane, w, q1, r31,
               (const short8*)(ws + W1A_OFF) + e * 4096,
               (const float*)(ws + B1E_OFF) + e * 512);
  mlp_layer<32>(smem, lane, w, q1, r31,
                (const short8*)(ws + W2A_OFF) + e * 32768, b2 + e * 512);
  mlp_layer<32>(smem, lane, w, q1, r31,
                (const short8*)(ws + W3A_OFF) + e * 32768, b3 + e * 512);

  // ---- layer 4: 8 tiles (o4 = w>>2, nt4 = w&3), full K per wave ----
  {
    const short8* A4 = (const short8*)(ws + W4A_OFF) + e * 4096;
    const short8* Ap = A4 + (w >> 2) * 64 + lane;  // granule (kc*2+o4)*64+lane
    const int nt4 = w & 3;
    const int fe0 = (w >> 2) * 32 + 4 * q1;
    floatx16 acc;
#pragma unroll
    for (int g = 0; g < 4; ++g) {
      floatx4 bv = *(const floatx4*)(b4 + e * 64 + fe0 + 8 * g);
      acc[4 * g + 0] = bv[0]; acc[4 * g + 1] = bv[1];
      acc[4 * g + 2] = bv[2]; acc[4 * g + 3] = bv[3];
    }
    short8 a0 = Ap[0], a1 = Ap[128];
    short8 b0 = *(const short8*)(smem + ((nt4 * 64 + lane) << 4));
#pragma unroll 4
    for (int kc = 0; kc < 32; ++kc) {
      short8 ac = a0; a0 = a1;
      a1 = Ap[(kc + 2) * 128];
      short8 bc = b0;
      b0 = *(const short8*)(smem + (((kc + 1) * 260 + nt4 * 64 + lane) << 4));
      acc = mfma32(ac, bc, acc);
    }
    const int row = row0 + nt4 * 32 + r31;
    const float sc = ew[row * 8 + e];
    float* orow = out + row * 64 + fe0;
#pragma unroll
    for (int g = 0; g < 4; ++g) {
      atomicAdd(orow + 8 * g + 0, acc[4 * g + 0] * sc);
      atomicAdd(orow + 8 * g + 1, acc[4 * g + 1] * sc);
      atomicAdd(orow + 8 * g + 2, acc[4 * g + 2] * sc);
      atomicAdd(orow + 8 * g + 3, acc[4 * g + 3] * sc);
    }
  }
}

extern "C" void kernel_launch(void* const* d_in, const int* in_sizes, int n_in,
                              void* d_out, int out_size, void* d_ws, size_t ws_size,
                              hipStream_t stream) {
  const float* t  = (const float*)d_in[0];
  const float* x  = (const float*)d_in[1];
  const float* ew = (const float*)d_in[2];
  const float* om = (const float*)d_in[3];
  const float* W1 = (const float*)d_in[4];
  const float* b1 = (const float*)d_in[5];
  const float* W2 = (const float*)d_in[6];
  const float* b2 = (const float*)d_in[7];
  const float* W3 = (const float*)d_in[8];
  const float* b3 = (const float*)d_in[9];
  const float* W4 = (const float*)d_in[10];
  const float* b4 = (const float*)d_in[11];
  char* ws = (char*)d_ws;
  float* out = (float*)d_out;
  (void)in_sizes; (void)n_in; (void)ws_size;

  hipMemsetAsync(out, 0, (size_t)out_size * sizeof(float), stream);
  // granule threads: 32768+262144+262144+32768+262144+4096 = 856064 = 3344*256
  prep_kernel<<<3344, 256, 0, stream>>>(t, x, om, W1, b1, W2, W3, W4, ws);
  fused_kernel<<<2048, 512, 0, stream>>>(ws, b2, b3, b4, ew, out);
}

// Round 4
// 599.109 us; speedup vs baseline: 1.1581x; 1.1581x over previous
//
#include <hip/hip_runtime.h>
#include <hip/hip_bf16.h>

// ExpertODEEnsemble: E=8, D=64, H=512, B=32768.
// R4: back to 64-row tiles / 2 blocks/CU (R2 geometry) + register double-buffer
// for B ds_reads, depth-2 A prefetch from L2, Pade tanh epilogue with bias in
// acc init, conflict-free layer-4 reduction addressing.

typedef unsigned short ushort_t;
typedef unsigned int u32;
typedef unsigned long long u64;
typedef __attribute__((ext_vector_type(8))) short short8;
typedef __attribute__((ext_vector_type(4))) float floatx4;
typedef __attribute__((ext_vector_type(16))) float floatx16;
typedef __attribute__((ext_vector_type(4))) int intx4;

// ws layout (bytes); granule = 16 B = 8 bf16 along k
#define W1A_OFF 0u          // per e: [kc0..3][o0..15][lane]   4096 granules
#define W2A_OFF 524288u     // per e: [kc0..31][o0..15][lane] 32768 granules
#define W3A_OFF 4718592u
#define W4A_OFF 8912896u    // per e: [kc0..31][o0..1][lane]   4096 granules
#define XB_OFF  9437184u    // x row-major bf16 [32768][64]
#define B1E_OFF 13631488u   // b1_eff fp32 [8][512]

static __device__ __forceinline__ u32 pk2bf(float a, float b) {
  union { __hip_bfloat162 h; u32 u; } v;
  v.h = __float22bfloat162_rn(make_float2(a, b));
  return v.u;
}

static __device__ __forceinline__ float pade_tanh(float x) {
  // tanh x = x(945+105x^2+x^4)/(945+420x^2+15x^4); |err|<=1e-4 for |x|<=2
  float x2 = x * x;
  float num = __builtin_fmaf(x2, __builtin_fmaf(x2, 1.0f, 105.0f), 945.0f);
  float den = __builtin_fmaf(x2, __builtin_fmaf(x2, 15.0f, 420.0f), 945.0f);
  return x * num * __builtin_amdgcn_rcpf(den);
}

static __device__ __forceinline__ void ald16(const void* g, void* l) {
  __builtin_amdgcn_global_load_lds((__attribute__((address_space(1))) void*)g,
                                   (__attribute__((address_space(3))) void*)l,
                                   16, 0, 0);
}

static __device__ __forceinline__ floatx16 mfma32(short8 a, short8 b, floatx16 c) {
  return __builtin_amdgcn_mfma_f32_32x32x16_bf16(a, b, c, 0, 0, 0);
}

// ---------------- prep: one 16B granule per thread, float4 reads -------------
__global__ __launch_bounds__(256) void prep_kernel(
    const float* __restrict__ t, const float* __restrict__ x,
    const float* __restrict__ omega, const float* __restrict__ W1,
    const float* __restrict__ b1, const float* __restrict__ W2,
    const float* __restrict__ W3, const float* __restrict__ W4,
    char* __restrict__ ws) {
  int i = blockIdx.x * 256 + threadIdx.x;
  if (i < 32768) {                       // W1A (stride 67 -> scalar reads)
    int e = i >> 12, r = i & 4095;
    int lane = r & 63, og = r >> 6, o = og & 15, kc = og >> 4;
    int outr = o * 32 + (lane & 31), k0 = kc * 16 + (lane >> 5) * 8;
    const float* s = W1 + (e * 512 + outr) * 67 + k0;
    ((intx4*)(ws + W1A_OFF))[i] = (intx4){
        (int)pk2bf(s[0], s[1]), (int)pk2bf(s[2], s[3]),
        (int)pk2bf(s[4], s[5]), (int)pk2bf(s[6], s[7])};
    return;
  }
  i -= 32768;
  if (i < 262144) {                      // W2A
    int e = i >> 15, r = i & 32767;
    int lane = r & 63, og = r >> 6, o = og & 15, kc = og >> 4;
    int outr = o * 32 + (lane & 31), k0 = kc * 16 + (lane >> 5) * 8;
    const floatx4* s = (const floatx4*)(W2 + (e * 512 + outr) * 512 + k0);
    floatx4 lo = s[0], hi = s[1];
    ((intx4*)(ws + W2A_OFF))[i] = (intx4){
        (int)pk2bf(lo[0], lo[1]), (int)pk2bf(lo[2], lo[3]),
        (int)pk2bf(hi[0], hi[1]), (int)pk2bf(hi[2], hi[3])};
    return;
  }
  i -= 262144;
  if (i < 262144) {                      // W3A
    int e = i >> 15, r = i & 32767;
    int lane = r & 63, og = r >> 6, o = og & 15, kc = og >> 4;
    int outr = o * 32 + (lane & 31), k0 = kc * 16 + (lane >> 5) * 8;
    const floatx4* s = (const floatx4*)(W3 + (e * 512 + outr) * 512 + k0);
    floatx4 lo = s[0], hi = s[1];
    ((intx4*)(ws + W3A_OFF))[i] = (intx4){
        (int)pk2bf(lo[0], lo[1]), (int)pk2bf(lo[2], lo[3]),
        (int)pk2bf(hi[0], hi[1]), (int)pk2bf(hi[2], hi[3])};
    return;
  }
  i -= 262144;
  if (i < 32768) {                       // W4A
    int e = i >> 12, r = i & 4095;
    int lane = r & 63, og = r >> 6, o = og & 1, kc = og >> 1;
    int outr = o * 32 + (lane & 31), k0 = kc * 16 + (lane >> 5) * 8;
    const floatx4* s = (const floatx4*)(W4 + (e * 64 + outr) * 512 + k0);
    floatx4 lo = s[0], hi = s[1];
    ((intx4*)(ws + W4A_OFF))[i] = (intx4){
        (int)pk2bf(lo[0], lo[1]), (int)pk2bf(lo[2], lo[3]),
        (int)pk2bf(hi[0], hi[1]), (int)pk2bf(hi[2], hi[3])};
    return;
  }
  i -= 32768;
  if (i < 262144) {                      // x -> bf16, row-major
    const floatx4* s = (const floatx4*)(x + i * 8);
    floatx4 lo = s[0], hi = s[1];
    ((intx4*)(ws + XB_OFF))[i] = (intx4){
        (int)pk2bf(lo[0], lo[1]), (int)pk2bf(lo[2], lo[3]),
        (int)pk2bf(hi[0], hi[1]), (int)pk2bf(hi[2], hi[3])};
    return;
  }
  i -= 262144;
  if (i < 4096) {                        // b1_eff: fold t/sin/cos cols of W1
    float tv = t[0];
    int e = i >> 9;
    float om = omega[e];
    ((float*)(ws + B1E_OFF))[i] = b1[i] + tv * W1[i * 67 + 64]
        + sinf(om * tv) * W1[i * 67 + 65] + cosf(om * tv) * W1[i * 67 + 66];
  }
}

// act LDS (64 rows): granule f(row, koct) = (koct>>1)*132 + (row>>5)*64
//                    + (koct&1)*32 + (row&31); koct 0..63, rows 0..63.
// B-frag (kc,nt): granules kc*132 + nt*64 + lane -> stride-1 1KB, conflict-free.

template <int NKC>
static __device__ __forceinline__ void mlp_layer(
    char* __restrict__ smem, int lane, int w, int q1, int r31,
    const short8* __restrict__ A, const float* __restrict__ bias) {
  const short8* Ap = A + (2 * w) * 64 + lane;   // granule (kc*16 + 2w+ol)*64+lane
  floatx16 acc[2][2];
#pragma unroll
  for (int ol = 0; ol < 2; ++ol) {
    int fe0 = (2 * w + ol) * 32 + 4 * q1;
#pragma unroll
    for (int g = 0; g < 4; ++g) {
      floatx4 bv = *(const floatx4*)(bias + fe0 + 8 * g);
#pragma unroll
      for (int nt = 0; nt < 2; ++nt) {
        acc[ol][nt][4 * g + 0] = bv[0];
        acc[ol][nt][4 * g + 1] = bv[1];
        acc[ol][nt][4 * g + 2] = bv[2];
        acc[ol][nt][4 * g + 3] = bv[3];
      }
    }
  }
  // depth-2 A prefetch (L2 ~200cyc), depth-2 B prefetch (LDS ~120cyc)
  short8 a_c[2], a_n[2], b_c[2], b_n[2];
  a_c[0] = Ap[0];    a_c[1] = Ap[64];
  a_n[0] = Ap[1024]; a_n[1] = Ap[1024 + 64];
  b_c[0] = *(const short8*)(smem + ((0 * 132 + 0 * 64 + lane) << 4));
  b_c[1] = *(const short8*)(smem + ((0 * 132 + 1 * 64 + lane) << 4));
  b_n[0] = *(const short8*)(smem + ((1 * 132 + 0 * 64 + lane) << 4));
  b_n[1] = *(const short8*)(smem + ((1 * 132 + 1 * 64 + lane) << 4));

#pragma unroll 4
  for (int kc = 0; kc < NKC; ++kc) {
    short8 ac0 = a_c[0], ac1 = a_c[1], bc0 = b_c[0], bc1 = b_c[1];
    a_c[0] = a_n[0]; a_c[1] = a_n[1];
    b_c[0] = b_n[0]; b_c[1] = b_n[1];
    a_n[0] = Ap[(kc + 2) * 1024];                // unguarded: lands in ws, unused
    a_n[1] = Ap[(kc + 2) * 1024 + 64];
    b_n[0] = *(const short8*)(smem + (((kc + 2) * 132 + 0 * 64 + lane) << 4));
    b_n[1] = *(const short8*)(smem + (((kc + 2) * 132 + 1 * 64 + lane) << 4));
    acc[0][0] = mfma32(ac0, bc0, acc[0][0]);
    acc[0][1] = mfma32(ac0, bc1, acc[0][1]);
    acc[1][0] = mfma32(ac1, bc0, acc[1][0]);
    acc[1][1] = mfma32(ac1, bc1, acc[1][1]);
  }
  __syncthreads();                               // all B reads done
#pragma unroll
  for (int ol = 0; ol < 2; ++ol) {
    int o_abs = 2 * w + ol;
#pragma unroll
    for (int g = 0; g < 4; ++g) {
      int koct = o_abs * 4 + g;
      char* base = smem + ((((koct >> 1) * 132 + (koct & 1) * 32 + r31) << 4) + q1 * 8);
#pragma unroll
      for (int nt = 0; nt < 2; ++nt) {
        float v0 = pade_tanh(acc[ol][nt][4 * g + 0]);
        float v1 = pade_tanh(acc[ol][nt][4 * g + 1]);
        float v2 = pade_tanh(acc[ol][nt][4 * g + 2]);
        float v3 = pade_tanh(acc[ol][nt][4 * g + 3]);
        u32 lo = pk2bf(v0, v1), hi = pk2bf(v2, v3);
        *(u64*)(base + nt * 1024) = ((u64)hi << 32) | lo;
      }
    }
  }
  __syncthreads();                               // act_{n+1} visible
}

__global__ __launch_bounds__(512, 4) void fused_kernel(
    const char* __restrict__ ws, const float* __restrict__ b2,
    const float* __restrict__ b3, const float* __restrict__ b4,
    const float* __restrict__ ew, float* __restrict__ out) {
  __shared__ char smem[71808];           // 32*132*16 act + pad for depth-2 pf
  const int t = threadIdx.x, lane = t & 63, w = t >> 6;
  const int q1 = lane >> 5, r31 = lane & 31;
  const int e = blockIdx.x & 7;          // expert -> XCD L2 affinity
  const int row0 = (blockIdx.x >> 3) << 6;       // 64-row tile

  // stage x (kc 0..3): 1 shot/wave, wave-uniform LDS base + lane*16
  const ushort_t* xb = (const ushort_t*)(ws + XB_OFF);
  ald16(xb + (row0 + (w & 1) * 32 + r31) * 64 + ((w >> 1) * 2 + q1) * 8,
        smem + (((w >> 1) * 132 + (w & 1) * 64) << 4));
  __syncthreads();

  mlp_layer<4>(smem, lane, w, q1, r31,
               (const short8*)(ws + W1A_OFF) + e * 4096,
               (const float*)(ws + B1E_OFF) + e * 512);
  mlp_layer<32>(smem, lane, w, q1, r31,
                (const short8*)(ws + W2A_OFF) + e * 32768, b2 + e * 512);
  mlp_layer<32>(smem, lane, w, q1, r31,
                (const short8*)(ws + W3A_OFF) + e * 32768, b3 + e * 512);

  // ---- layer 4: tiles (o4 = w&1, nt4 = (w>>1)&1), K halves kh = w>>2 ----
  {
    const short8* A4 = (const short8*)(ws + W4A_OFF) + e * 4096;
    const int o4 = w & 1, nt4 = (w >> 1) & 1, kh = w >> 2;
    const short8* Ap = A4 + o4 * 64 + lane;      // granule (kc*2 + o4)*64 + lane
    floatx16 acc = {};
    short8 a_c = Ap[(kh * 16) * 128], a_n = Ap[(kh * 16 + 1) * 128];
    short8 b_c = *(const short8*)(smem + (((kh * 16) * 132 + nt4 * 64 + lane) << 4));
    short8 b_n = *(const short8*)(smem + (((kh * 16 + 1) * 132 + nt4 * 64 + lane) << 4));
#pragma unroll 4
    for (int kc = kh * 16; kc < kh * 16 + 16; ++kc) {
      short8 ac = a_c, bc = b_c;
      a_c = a_n; b_c = b_n;
      a_n = Ap[(kc + 2) * 128];                  // unguarded: in-ws
      b_n = *(const short8*)(smem + (((kc + 2) * 132 + nt4 * 64 + lane) << 4));
      acc = mfma32(ac, bc, acc);
    }
    __syncthreads();                     // act region now dead
    if (w >= 4) {                        // conflict-free exchange: 16B/lane
#pragma unroll
      for (int i = 0; i < 4; ++i) {
        floatx4 p = {acc[i * 4 + 0], acc[i * 4 + 1], acc[i * 4 + 2], acc[i * 4 + 3]};
        *(floatx4*)(smem + (w - 4) * 4096 + i * 1024 + lane * 16) = p;
      }
    }
    __syncthreads();
    if (w < 4) {
#pragma unroll
      for (int i = 0; i < 4; ++i) {
        floatx4 p = *(const floatx4*)(smem + w * 4096 + i * 1024 + lane * 16);
        acc[i * 4 + 0] += p[0]; acc[i * 4 + 1] += p[1];
        acc[i * 4 + 2] += p[2]; acc[i * 4 + 3] += p[3];
      }
      const int row = row0 + nt4 * 32 + r31;
      const float sc = ew[row * 8 + e];
      const int fe0 = o4 * 32 + 4 * q1;
      float* orow = out + row * 64 + fe0;
      const float* bp = b4 + e * 64 + fe0;
#pragma unroll
      for (int g = 0; g < 4; ++g) {
        floatx4 bv = *(const floatx4*)(bp + 8 * g);
        atomicAdd(orow + 8 * g + 0, (acc[4 * g + 0] + bv[0]) * sc);
        atomicAdd(orow + 8 * g + 1, (acc[4 * g + 1] + bv[1]) * sc);
        atomicAdd(orow + 8 * g + 2, (acc[4 * g + 2] + bv[2]) * sc);
        atomicAdd(orow + 8 * g + 3, (acc[4 * g + 3] + bv[3]) * sc);
      }
    }
  }
}

extern "C" void kernel_launch(void* const* d_in, const int* in_sizes, int n_in,
                              void* d_out, int out_size, void* d_ws, size_t ws_size,
                              hipStream_t stream) {
  const float* t  = (const float*)d_in[0];
  const float* x  = (const float*)d_in[1];
  const float* ew = (const float*)d_in[2];
  const float* om = (const float*)d_in[3];
  const float* W1 = (const float*)d_in[4];
  const float* b1 = (const float*)d_in[5];
  const float* W2 = (const float*)d_in[6];
  const float* b2 = (const float*)d_in[7];
  const float* W3 = (const float*)d_in[8];
  const float* b3 = (const float*)d_in[9];
  const float* W4 = (const float*)d_in[10];
  const float* b4 = (const float*)d_in[11];
  char* ws = (char*)d_ws;
  float* out = (float*)d_out;
  (void)in_sizes; (void)n_in; (void)ws_size;

  hipMemsetAsync(out, 0, (size_t)out_size * sizeof(float), stream);
  // granule threads: 32768+262144+262144+32768+262144+4096 = 856064 = 3344*256
  prep_kernel<<<3344, 256, 0, stream>>>(t, x, om, W1, b1, W2, W3, W4, ws);
  fused_kernel<<<4096, 512, 0, stream>>>(ws, b2, b3, b4, ew, out);
}

// Round 5
// 541.051 us; speedup vs baseline: 1.2824x; 1.1073x over previous
//
#include <hip/hip_runtime.h>
#include <hip/hip_bf16.h>

// ExpertODEEnsemble: E=8, D=64, H=512, B=32768.
// R5: one block = 64-row tile, loops over all 8 experts (XCD-staggered order),
// weighted combine in registers -> zero atomics, plain stores. x staged once.
// Inner structure = R4 (A via VGPR depth-2 prefetch, B depth-2 ds_read,
// 32x32x16 MFMA, Pade tanh epilogue, bias in acc init).

typedef unsigned short ushort_t;
typedef unsigned int u32;
typedef unsigned long long u64;
typedef __attribute__((ext_vector_type(8))) short short8;
typedef __attribute__((ext_vector_type(4))) float floatx4;
typedef __attribute__((ext_vector_type(16))) float floatx16;
typedef __attribute__((ext_vector_type(4))) int intx4;

// ws layout (bytes); granule = 16 B = 8 bf16 along k
#define W1A_OFF 0u          // per e: [kc0..3][o0..15][lane]   4096 granules
#define W2A_OFF 524288u     // per e: [kc0..31][o0..15][lane] 32768 granules
#define W3A_OFF 4718592u
#define W4A_OFF 8912896u    // per e: [kc0..31][o0..1][lane]   4096 granules
#define XB_OFF  9437184u    // x row-major bf16 [32768][64]
#define B1E_OFF 13631488u   // b1_eff fp32 [8][512]

static __device__ __forceinline__ u32 pk2bf(float a, float b) {
  union { __hip_bfloat162 h; u32 u; } v;
  v.h = __float22bfloat162_rn(make_float2(a, b));
  return v.u;
}

static __device__ __forceinline__ float pade_tanh(float x) {
  // tanh x = x(945+105x^2+x^4)/(945+420x^2+15x^4); |err|<=1e-4 for |x|<=2
  float x2 = x * x;
  float num = __builtin_fmaf(x2, __builtin_fmaf(x2, 1.0f, 105.0f), 945.0f);
  float den = __builtin_fmaf(x2, __builtin_fmaf(x2, 15.0f, 420.0f), 945.0f);
  return x * num * __builtin_amdgcn_rcpf(den);
}

static __device__ __forceinline__ void ald16(const void* g, void* l) {
  __builtin_amdgcn_global_load_lds((__attribute__((address_space(1))) void*)g,
                                   (__attribute__((address_space(3))) void*)l,
                                   16, 0, 0);
}

static __device__ __forceinline__ floatx16 mfma32(short8 a, short8 b, floatx16 c) {
  return __builtin_amdgcn_mfma_f32_32x32x16_bf16(a, b, c, 0, 0, 0);
}

// ---------------- prep: one 16B granule per thread, float4 reads -------------
__global__ __launch_bounds__(256) void prep_kernel(
    const float* __restrict__ t, const float* __restrict__ x,
    const float* __restrict__ omega, const float* __restrict__ W1,
    const float* __restrict__ b1, const float* __restrict__ W2,
    const float* __restrict__ W3, const float* __restrict__ W4,
    char* __restrict__ ws) {
  int i = blockIdx.x * 256 + threadIdx.x;
  if (i < 32768) {                       // W1A (stride 67 -> scalar reads)
    int e = i >> 12, r = i & 4095;
    int lane = r & 63, og = r >> 6, o = og & 15, kc = og >> 4;
    int outr = o * 32 + (lane & 31), k0 = kc * 16 + (lane >> 5) * 8;
    const float* s = W1 + (e * 512 + outr) * 67 + k0;
    ((intx4*)(ws + W1A_OFF))[i] = (intx4){
        (int)pk2bf(s[0], s[1]), (int)pk2bf(s[2], s[3]),
        (int)pk2bf(s[4], s[5]), (int)pk2bf(s[6], s[7])};
    return;
  }
  i -= 32768;
  if (i < 262144) {                      // W2A
    int e = i >> 15, r = i & 32767;
    int lane = r & 63, og = r >> 6, o = og & 15, kc = og >> 4;
    int outr = o * 32 + (lane & 31), k0 = kc * 16 + (lane >> 5) * 8;
    const floatx4* s = (const floatx4*)(W2 + (e * 512 + outr) * 512 + k0);
    floatx4 lo = s[0], hi = s[1];
    ((intx4*)(ws + W2A_OFF))[i] = (intx4){
        (int)pk2bf(lo[0], lo[1]), (int)pk2bf(lo[2], lo[3]),
        (int)pk2bf(hi[0], hi[1]), (int)pk2bf(hi[2], hi[3])};
    return;
  }
  i -= 262144;
  if (i < 262144) {                      // W3A
    int e = i >> 15, r = i & 32767;
    int lane = r & 63, og = r >> 6, o = og & 15, kc = og >> 4;
    int outr = o * 32 + (lane & 31), k0 = kc * 16 + (lane >> 5) * 8;
    const floatx4* s = (const floatx4*)(W3 + (e * 512 + outr) * 512 + k0);
    floatx4 lo = s[0], hi = s[1];
    ((intx4*)(ws + W3A_OFF))[i] = (intx4){
        (int)pk2bf(lo[0], lo[1]), (int)pk2bf(lo[2], lo[3]),
        (int)pk2bf(hi[0], hi[1]), (int)pk2bf(hi[2], hi[3])};
    return;
  }
  i -= 262144;
  if (i < 32768) {                       // W4A
    int e = i >> 12, r = i & 4095;
    int lane = r & 63, og = r >> 6, o = og & 1, kc = og >> 1;
    int outr = o * 32 + (lane & 31), k0 = kc * 16 + (lane >> 5) * 8;
    const floatx4* s = (const floatx4*)(W4 + (e * 64 + outr) * 512 + k0);
    floatx4 lo = s[0], hi = s[1];
    ((intx4*)(ws + W4A_OFF))[i] = (intx4){
        (int)pk2bf(lo[0], lo[1]), (int)pk2bf(lo[2], lo[3]),
        (int)pk2bf(hi[0], hi[1]), (int)pk2bf(hi[2], hi[3])};
    return;
  }
  i -= 32768;
  if (i < 262144) {                      // x -> bf16, row-major
    const floatx4* s = (const floatx4*)(x + i * 8);
    floatx4 lo = s[0], hi = s[1];
    ((intx4*)(ws + XB_OFF))[i] = (intx4){
        (int)pk2bf(lo[0], lo[1]), (int)pk2bf(lo[2], lo[3]),
        (int)pk2bf(hi[0], hi[1]), (int)pk2bf(hi[2], hi[3])};
    return;
  }
  i -= 262144;
  if (i < 4096) {                        // b1_eff: fold t/sin/cos cols of W1
    float tv = t[0];
    int e = i >> 9;
    float om = omega[e];
    ((float*)(ws + B1E_OFF))[i] = b1[i] + tv * W1[i * 67 + 64]
        + sinf(om * tv) * W1[i * 67 + 65] + cosf(om * tv) * W1[i * 67 + 66];
  }
}

// act LDS (64 rows): granule f(row, koct) = (koct>>1)*132 + (row>>5)*64
//                    + (koct&1)*32 + (row&31); koct 0..63, rows 0..63.
// B-frag (kc,nt): granules kc*132 + nt*64 + lane -> stride-1 1KB, conflict-free.

template <int NKC, bool WRAP>
static __device__ __forceinline__ void mlp_layer(
    const char* __restrict__ bsrc, char* __restrict__ dst,
    int lane, int w, int q1, int r31,
    const short8* __restrict__ A, const float* __restrict__ bias) {
  const short8* Ap = A + (2 * w) * 64 + lane;   // granule (kc*16 + 2w+ol)*64+lane
  floatx16 acc[2][2];
#pragma unroll
  for (int ol = 0; ol < 2; ++ol) {
    int fe0 = (2 * w + ol) * 32 + 4 * q1;
#pragma unroll
    for (int g = 0; g < 4; ++g) {
      floatx4 bv = *(const floatx4*)(bias + fe0 + 8 * g);
#pragma unroll
      for (int nt = 0; nt < 2; ++nt) {
        acc[ol][nt][4 * g + 0] = bv[0];
        acc[ol][nt][4 * g + 1] = bv[1];
        acc[ol][nt][4 * g + 2] = bv[2];
        acc[ol][nt][4 * g + 3] = bv[3];
      }
    }
  }
  // depth-2 A prefetch (L2 ~200cyc), depth-2 B prefetch (LDS ~120cyc)
  short8 a_c[2], a_n[2], b_c[2], b_n[2];
  a_c[0] = Ap[0];    a_c[1] = Ap[64];
  a_n[0] = Ap[1024]; a_n[1] = Ap[1024 + 64];
  b_c[0] = *(const short8*)(bsrc + ((0 * 132 + 0 * 64 + lane) << 4));
  b_c[1] = *(const short8*)(bsrc + ((0 * 132 + 1 * 64 + lane) << 4));
  b_n[0] = *(const short8*)(bsrc + ((1 * 132 + 0 * 64 + lane) << 4));
  b_n[1] = *(const short8*)(bsrc + ((1 * 132 + 1 * 64 + lane) << 4));

#pragma unroll 4
  for (int kc = 0; kc < NKC; ++kc) {
    short8 ac0 = a_c[0], ac1 = a_c[1], bc0 = b_c[0], bc1 = b_c[1];
    a_c[0] = a_n[0]; a_c[1] = a_n[1];
    b_c[0] = b_n[0]; b_c[1] = b_n[1];
    a_n[0] = Ap[(kc + 2) * 1024];                // unguarded: lands in ws, unused
    a_n[1] = Ap[(kc + 2) * 1024 + 64];
    const int kp = WRAP ? ((kc + 2) & (NKC - 1)) : (kc + 2);
    b_n[0] = *(const short8*)(bsrc + ((kp * 132 + 0 * 64 + lane) << 4));
    b_n[1] = *(const short8*)(bsrc + ((kp * 132 + 1 * 64 + lane) << 4));
    acc[0][0] = mfma32(ac0, bc0, acc[0][0]);
    acc[0][1] = mfma32(ac0, bc1, acc[0][1]);
    acc[1][0] = mfma32(ac1, bc0, acc[1][0]);
    acc[1][1] = mfma32(ac1, bc1, acc[1][1]);
  }
  __syncthreads();                               // all act reads (prev layer/L4) done
#pragma unroll
  for (int ol = 0; ol < 2; ++ol) {
    int o_abs = 2 * w + ol;
#pragma unroll
    for (int g = 0; g < 4; ++g) {
      int koct = o_abs * 4 + g;
      char* base = dst + ((((koct >> 1) * 132 + (koct & 1) * 32 + r31) << 4) + q1 * 8);
#pragma unroll
      for (int nt = 0; nt < 2; ++nt) {
        float v0 = pade_tanh(acc[ol][nt][4 * g + 0]);
        float v1 = pade_tanh(acc[ol][nt][4 * g + 1]);
        float v2 = pade_tanh(acc[ol][nt][4 * g + 2]);
        float v3 = pade_tanh(acc[ol][nt][4 * g + 3]);
        u32 lo = pk2bf(v0, v1), hi = pk2bf(v2, v3);
        *(u64*)(base + nt * 1024) = ((u64)hi << 32) | lo;
      }
    }
  }
  __syncthreads();                               // act_{n+1} visible
}

__global__ __launch_bounds__(512, 4) void fused_kernel(
    const char* __restrict__ ws, const float* __restrict__ b2,
    const float* __restrict__ b3, const float* __restrict__ b4,
    const float* __restrict__ ew, float* __restrict__ out) {
  __shared__ char smem[80256];           // 71808 act (+pf pad) | 8448 x region
  char* xreg = smem + 71808;
  const int t = threadIdx.x, lane = t & 63, w = t >> 6;
  const int q1 = lane >> 5, r31 = lane & 31;
  const int xcd = blockIdx.x & 7;        // XCD proxy for expert stagger
  const int row0 = blockIdx.x << 6;      // 64-row tile, 512 blocks

  // stage x once (kc 0..3): 1 shot/wave into x region
  const ushort_t* xb = (const ushort_t*)(ws + XB_OFF);
  ald16(xb + (row0 + (w & 1) * 32 + r31) * 64 + ((w >> 1) * 2 + q1) * 8,
        xreg + (((w >> 1) * 132 + (w & 1) * 64) << 4));

  // L4 tile assignment (fixed per wave): o4 feats-half, nt4 rows-half, kh K-half
  const int o4 = w & 1, nt4 = (w >> 1) & 1, kh = w >> 2;
  const int row_l4 = row0 + nt4 * 32 + r31;
  const int fe0 = o4 * 32 + 4 * q1;
  floatx16 out_acc = {};

  __syncthreads();                       // x staged

  const short8* W1A = (const short8*)(ws + W1A_OFF);
  const short8* W2A = (const short8*)(ws + W2A_OFF);
  const short8* W3A = (const short8*)(ws + W3A_OFF);
  const short8* W4A = (const short8*)(ws + W4A_OFF);
  const float* B1E = (const float*)(ws + B1E_OFF);

  for (int ei = 0; ei < 8; ++ei) {
    const int e = (xcd + ei) & 7;
    const float sc = ew[row_l4 * 8 + e];

    mlp_layer<4, true>(xreg, smem, lane, w, q1, r31, W1A + e * 4096, B1E + e * 512);
    mlp_layer<32, false>(smem, smem, lane, w, q1, r31, W2A + e * 32768, b2 + e * 512);
    mlp_layer<32, false>(smem, smem, lane, w, q1, r31, W3A + e * 32768, b3 + e * 512);

    // L4: K-half kh, tile (o4, nt4); reads act, no LDS writes (next L1's
    // first barrier protects act before its epilogue overwrites it).
    {
      const short8* Ap = W4A + e * 4096 + o4 * 64 + lane;
      floatx16 acc = {};
      short8 a_c = Ap[(kh * 16) * 128], a_n = Ap[(kh * 16 + 1) * 128];
      short8 b_c = *(const short8*)(smem + (((kh * 16) * 132 + nt4 * 64 + lane) << 4));
      short8 b_n = *(const short8*)(smem + (((kh * 16 + 1) * 132 + nt4 * 64 + lane) << 4));
#pragma unroll 4
      for (int kc = kh * 16; kc < kh * 16 + 16; ++kc) {
        short8 ac = a_c, bc = b_c;
        a_c = a_n; b_c = b_n;
        a_n = Ap[(kc + 2) * 128];                // unguarded: in-ws
        b_n = *(const short8*)(smem + (((kc + 2) * 132 + nt4 * 64 + lane) << 4));
        acc = mfma32(ac, bc, acc);
      }
      if (kh == 0) {                     // add bias once (kh=0 partner only)
        const float* bp = b4 + e * 64 + fe0;
#pragma unroll
        for (int g = 0; g < 4; ++g) {
          floatx4 bv = *(const floatx4*)(bp + 8 * g);
          out_acc[4 * g + 0] += sc * (acc[4 * g + 0] + bv[0]);
          out_acc[4 * g + 1] += sc * (acc[4 * g + 1] + bv[1]);
          out_acc[4 * g + 2] += sc * (acc[4 * g + 2] + bv[2]);
          out_acc[4 * g + 3] += sc * (acc[4 * g + 3] + bv[3]);
        }
      } else {
#pragma unroll
        for (int i = 0; i < 16; ++i) out_acc[i] += sc * acc[i];
      }
    }
  }

  // final: merge K-half partners via LDS (act region dead), plain stores
  __syncthreads();
  if (w >= 4) {
#pragma unroll
    for (int i = 0; i < 4; ++i) {
      floatx4 p = {out_acc[i * 4 + 0], out_acc[i * 4 + 1],
                   out_acc[i * 4 + 2], out_acc[i * 4 + 3]};
      *(floatx4*)(smem + (w - 4) * 4096 + i * 1024 + lane * 16) = p;
    }
  }
  __syncthreads();
  if (w < 4) {
    float* orow = out + row_l4 * 64 + fe0;
#pragma unroll
    for (int g = 0; g < 4; ++g) {
      floatx4 p = *(const floatx4*)(smem + w * 4096 + g * 1024 + lane * 16);
      floatx4 v = {out_acc[4 * g + 0] + p[0], out_acc[4 * g + 1] + p[1],
                   out_acc[4 * g + 2] + p[2], out_acc[4 * g + 3] + p[3]};
      *(floatx4*)(orow + 8 * g) = v;
    }
  }
}

extern "C" void kernel_launch(void* const* d_in, const int* in_sizes, int n_in,
                              void* d_out, int out_size, void* d_ws, size_t ws_size,
                              hipStream_t stream) {
  const float* t  = (const float*)d_in[0];
  const float* x  = (const float*)d_in[1];
  const float* ew = (const float*)d_in[2];
  const float* om = (const float*)d_in[3];
  const float* W1 = (const float*)d_in[4];
  const float* b1 = (const float*)d_in[5];
  const float* W2 = (const float*)d_in[6];
  const float* b2 = (const float*)d_in[7];
  const float* W3 = (const float*)d_in[8];
  const float* b3 = (const float*)d_in[9];
  const float* W4 = (const float*)d_in[10];
  const float* b4 = (const float*)d_in[11];
  char* ws = (char*)d_ws;
  float* out = (float*)d_out;
  (void)in_sizes; (void)n_in; (void)ws_size; (void)out_size;

  // granule threads: 32768+262144+262144+32768+262144+4096 = 856064 = 3344*256
  prep_kernel<<<3344, 256, 0, stream>>>(t, x, om, W1, b1, W2, W3, W4, ws);
  fused_kernel<<<512, 512, 0, stream>>>(ws, b2, b3, b4, ew, out);
}